// Round 14
// baseline (210.789 us; speedup 1.0000x reference)
//
#include <hip/hip_runtime.h>

typedef __bf16 bf16;
typedef __attribute__((ext_vector_type(4))) __bf16 bf16x4;
typedef __attribute__((ext_vector_type(8))) __bf16 bf16x8;
typedef __attribute__((ext_vector_type(4))) float f32x4;

#define B_   4
#define T_   2048
#define C_   768
#define H_   8
#define HS_  96
#define M_   (B_ * T_)      /* 8192 */
#define QKN_ (3 * C_)       /* 2304 */

#define NEG_BIG (-1e30f)

// LDS strides (elements) for attn tiles (r10 values — known-good)
#define KSTR 104   /* 64x(96) K tile rows, padded 96->104 */
#define VSTR 72    /* 96x(64) Vt tile rows, padded 64->72 */

// ---------------------------------------------------------------------------
// async global->LDS, 16B per lane. LDS dest must be wave-uniform base;
// HW writes base + lane*16 (m104). Global addr is per-lane.
// ---------------------------------------------------------------------------
__device__ __forceinline__ void gload_lds16(const bf16* g, bf16* l) {
    __builtin_amdgcn_global_load_lds(
        (const __attribute__((address_space(1))) uint32_t*)g,
        (__attribute__((address_space(3))) uint32_t*)l,
        16, 0, 0);
}

__device__ __forceinline__ bf16x8 cvt8(f32x4 v0, f32x4 v1) {
    bf16x8 o;
#pragma unroll
    for (int i = 0; i < 4; ++i) { o[i] = (bf16)v0[i]; o[4 + i] = (bf16)v1[i]; }
    return o;
}

// ---------------------------------------------------------------------------
// Transpose + convert: W[R][Cn] (fp32) -> Wt[Cn][R] (bf16)  (path-B fallback)
// ---------------------------------------------------------------------------
__global__ void transpose_kernel(const float* __restrict__ W, bf16* __restrict__ Wt,
                                 int R, int Cn) {
    __shared__ bf16 tile[32][33];
    int tx = threadIdx.x, ty = threadIdx.y;
    int x  = blockIdx.x * 32 + tx;
    int y0 = blockIdx.y * 32;
#pragma unroll
    for (int j = 0; j < 32; j += 8)
        tile[ty + j][tx] = (bf16)W[(size_t)(y0 + ty + j) * Cn + x];
    __syncthreads();
    int y2 = blockIdx.x * 32;
    int x2 = y0 + tx;
#pragma unroll
    for (int j = 0; j < 32; j += 8)
        Wt[(size_t)(y2 + ty + j) * R + x2] = tile[tx][ty + j];
}

// ---------------------------------------------------------------------------
__global__ void sentinel_kernel(float* __restrict__ out, int n) {
    int i = blockIdx.x * 256 + threadIdx.x;
    if (i < n) out[i] = 12345.0f;
}

// ---------------------------------------------------------------------------
// One-shot fp32 -> bf16 convert (x -> xb)  (path-B fallback)
// ---------------------------------------------------------------------------
__global__ __launch_bounds__(256) void convert_bf16_kernel(const float* __restrict__ in,
                                                           bf16* __restrict__ out,
                                                           int n8) {
    int i = blockIdx.x * 256 + threadIdx.x;
    if (i >= n8) return;
    const float* p = in + (size_t)i * 8;
    f32x4 a = *(const f32x4*)p;
    f32x4 b = *(const f32x4*)(p + 4);
    *(bf16x8*)&out[(size_t)i * 8] = cvt8(a, b);
}

// ---------------------------------------------------------------------------
// Merged prep: convert x->xb (bf16) + transpose both weights, one launch.
// ---------------------------------------------------------------------------
#define CONV_BLKS (M_ * C_ / 8 / 256)          /* 3072 */
#define TA_BX (QKN_ / 32)                      /* 72 */
#define TA_BLKS (TA_BX * (C_ / 32))            /* 1728 */
#define TP_BX (C_ / 32)                        /* 24 */
#define TP_BLKS (TP_BX * (C_ / 32))            /* 576 */

__device__ __forceinline__ void transpose_body(bf16 (*tile)[33],
                                               const float* __restrict__ W,
                                               bf16* __restrict__ Wt,
                                               int R, int Cn, int bx, int by, int tid) {
    int tx = tid & 31, ty = tid >> 5;
    int x  = bx * 32 + tx;
    int y0 = by * 32;
#pragma unroll
    for (int j = 0; j < 32; j += 8)
        tile[ty + j][tx] = (bf16)W[(size_t)(y0 + ty + j) * Cn + x];
    __syncthreads();
    int y2 = bx * 32;
    int x2 = y0 + tx;
#pragma unroll
    for (int j = 0; j < 32; j += 8)
        Wt[(size_t)(y2 + ty + j) * R + x2] = tile[tx][ty + j];
}

__global__ __launch_bounds__(256) void prep_kernel(const float* __restrict__ x,
                                                   bf16* __restrict__ xb,
                                                   const float* __restrict__ Wa,
                                                   bf16* __restrict__ Wta,
                                                   const float* __restrict__ Wp,
                                                   bf16* __restrict__ Wtp) {
    __shared__ bf16 tile[32][33];
    int bid = blockIdx.x;
    int tid = threadIdx.x;
    if (bid < CONV_BLKS) {
        int i = bid * 256 + tid;
        const float* p = x + (size_t)i * 8;
        f32x4 a = *(const f32x4*)p;
        f32x4 b = *(const f32x4*)(p + 4);
        *(bf16x8*)&xb[(size_t)i * 8] = cvt8(a, b);
    } else if (bid < CONV_BLKS + TA_BLKS) {
        int t = bid - CONV_BLKS;
        transpose_body(tile, Wa, Wta, C_, QKN_, t % TA_BX, t / TA_BX, tid);
    } else {
        int t = bid - CONV_BLKS - TA_BLKS;
        transpose_body(tile, Wp, Wtp, C_, C_, t % TP_BX, t / TP_BX, tid);
    }
}

// ---------------------------------------------------------------------------
// GEMM1 r14 (= r13 with the LDS stride bug fixed): BK=32 double-buffer.
// BUG WAS: lA/lB segment base used seg*1024 (byte count used as element
// index) -> OOB LDS writes across buffers and into ldb -> NaN. A segment
// is 16 rows x 32 cols = 512 ELEMENTS; correct base is seg*512.
// LDS 64KB -> 16KB => LDS no longer caps occupancy (grid 1152 ~ 4.5/CU).
// Counted vmcnt(4); source-side XOR swizzle: slot (row,c) holds global
// chunk c^((row>>1)&3); fragment read at chunk quad^((col>>1)&3) => 2-way
// residual (free, m136). Vt epilogue k-permutes t within each 64-tile.
// ---------------------------------------------------------------------------
#define QK_ELEMS (128 * 32)
__global__ __launch_bounds__(256) void gemm_qkv(const bf16* __restrict__ A,
                                                const bf16* __restrict__ Bt,
                                                const float* __restrict__ bias,
                                                bf16* __restrict__ Cmat,
                                                bf16* __restrict__ Vt,
                                                int M, int N, int K) {
    __shared__ bf16 lda[2 * QK_ELEMS];
    __shared__ bf16 ldb[2 * QK_ELEMS];
    int tid  = threadIdx.x;
    int w    = tid >> 6;
    int lane = tid & 63;
    int col  = lane & 15, quad = lane >> 4;
    int wr   = w >> 1, wc = w & 1;
    int m0   = blockIdx.y * 128, n0 = blockIdx.x * 128;

    // staging: 8 segments of 16 rows x 32 cols (512 elems); wave w: segs
    // 2w, 2w+1. lane l -> row seg*16+(l>>2), slot chunk l&3; SOURCE chunk
    // (l&3)^((l>>3)&3).
    int srow = lane >> 2;
    int scol = ((lane & 3) ^ ((lane >> 3) & 3)) * 8;
    const bf16* gA[2]; const bf16* gB[2]; bf16* lA[2]; bf16* lB[2];
#pragma unroll
    for (int i = 0; i < 2; ++i) {
        int seg = w * 2 + i;
        int row = seg * 16 + srow;
        gA[i] = &A[(size_t)(m0 + row) * K + scol];
        gB[i] = &Bt[(size_t)(n0 + row) * K + scol];
        lA[i] = &lda[seg * 512];   // FIXED (was seg*1024: OOB)
        lB[i] = &ldb[seg * 512];   // FIXED
    }

    const f32x4 zero = {0.f, 0.f, 0.f, 0.f};
    f32x4 acc[4][4];
#pragma unroll
    for (int mr = 0; mr < 4; ++mr)
#pragma unroll
        for (int nc = 0; nc < 4; ++nc) acc[mr][nc] = zero;

    // prologue: stage tile 0 (4 loads/wave in flight, NOT drained)
#pragma unroll
    for (int i = 0; i < 2; ++i) {
        gload_lds16(gA[i], lA[i]);
        gload_lds16(gB[i], lB[i]);
    }

    int cur = 0;
    const int ca = (quad ^ ((col >> 1) & 3)) * 8;   // swizzled read chunk
    for (int k0 = 0; k0 < K; k0 += 32) {
        int nxt = cur ^ 1;
        if (k0 + 32 < K) {
#pragma unroll
            for (int i = 0; i < 2; ++i) {
                gload_lds16(gA[i] + k0 + 32, lA[i] + nxt * QK_ELEMS);
                gload_lds16(gB[i] + k0 + 32, lB[i] + nxt * QK_ELEMS);
            }
            asm volatile("s_waitcnt vmcnt(4)" ::: "memory");
        } else {
            asm volatile("s_waitcnt vmcnt(0)" ::: "memory");
        }
        __builtin_amdgcn_s_barrier();        // tile t landed for all waves
        __builtin_amdgcn_sched_barrier(0);   // no ds_read hoists above
        const bf16* la = &lda[cur * QK_ELEMS];
        const bf16* lb = &ldb[cur * QK_ELEMS];
        bf16x8 af[4], bfr[4];
#pragma unroll
        for (int t = 0; t < 4; ++t) {
            af[t]  = *(const bf16x8*)&la[(wr * 64 + t * 16 + col) * 32 + ca];
            bfr[t] = *(const bf16x8*)&lb[(wc * 64 + t * 16 + col) * 32 + ca];
        }
#pragma unroll
        for (int mr = 0; mr < 4; ++mr)
#pragma unroll
            for (int nc = 0; nc < 4; ++nc)
                acc[mr][nc] = __builtin_amdgcn_mfma_f32_16x16x32_bf16(
                    af[mr], bfr[nc], acc[mr][nc], 0, 0, 0);
        __builtin_amdgcn_sched_barrier(0);   // reads stay above the barrier
        __builtin_amdgcn_s_barrier();        // reads done before overwrite
        cur = nxt;
    }

#pragma unroll
    for (int nc = 0; nc < 4; ++nc) {
        int n = n0 + wc * 64 + nc * 16 + col;
        float bv = bias[n];
#pragma unroll
        for (int mr = 0; mr < 4; ++mr) {
#pragma unroll
            for (int r = 0; r < 4; ++r) {
                int row = m0 + wr * 64 + mr * 16 + quad * 4 + r;
                Cmat[(size_t)row * N + n] = (bf16)(acc[mr][nc][r] + bv);
            }
        }
    }
    if (n0 >= 2 * C_) {
        int batch = m0 >> 11;
        bf16* Vtb = Vt + (size_t)batch * C_ * T_;
        int t0 = (m0 & 2047) + wr * 64;
#pragma unroll
        for (int nc = 0; nc < 4; ++nc) {
            int n  = n0 + wc * 64 + nc * 16 + col;
            int vc = n - 2 * C_;
            float bv = bias[n];
#pragma unroll
            for (int mr = 0; mr < 4; ++mr) {
                int t  = t0 + mr * 16 + quad * 4;
                int tb = t & ~63;                 // 64-tile base
                int a  = (t >> 2) & 15;           // 4-chunk index in tile
                int ts = tb + ((a & 7) << 3) + ((a >> 3) << 2);  // permuted base
                bf16x4 pk = {(bf16)(acc[mr][nc][0] + bv), (bf16)(acc[mr][nc][1] + bv),
                             (bf16)(acc[mr][nc][2] + bv), (bf16)(acc[mr][nc][3] + bv)};
                *(bf16x4*)&Vtb[(size_t)vc * T_ + ts] = pk;
            }
        }
    }
}

#define TILE_ELEMS (128 * 64)

// ---------------------------------------------------------------------------
// GEMM2 — EXACT r10 structure (128x128, counted vmcnt(8), XOR swizzle).
// ---------------------------------------------------------------------------
__global__ __launch_bounds__(256) void gemm_proj(const bf16* __restrict__ A,
                                                 const bf16* __restrict__ Bt,
                                                 const float* __restrict__ bias,
                                                 float* __restrict__ Cmat,
                                                 int M, int N, int K) {
    __shared__ bf16 lda[2 * TILE_ELEMS];
    __shared__ bf16 ldb[2 * TILE_ELEMS];
    int tid  = threadIdx.x;
    int w    = tid >> 6;
    int lane = tid & 63;
    int col  = lane & 15, quad = lane >> 4;
    int wr   = w >> 1, wc = w & 1;
    int m0   = blockIdx.y * 128, n0 = blockIdx.x * 128;

    int srow = lane >> 3;
    int scol = ((lane & 7) ^ srow) * 8;
    const bf16* gA[4]; const bf16* gB[4]; bf16* lA[4]; bf16* lB[4];
#pragma unroll
    for (int i = 0; i < 4; ++i) {
        int seg = w * 4 + i;
        int row = seg * 8 + srow;
        gA[i] = &A[(size_t)(m0 + row) * K + scol];
        gB[i] = &Bt[(size_t)(n0 + row) * K + scol];
        lA[i] = &lda[seg * 512];
        lB[i] = &ldb[seg * 512];
    }

    const f32x4 zero = {0.f, 0.f, 0.f, 0.f};
    f32x4 acc[4][4];
#pragma unroll
    for (int mr = 0; mr < 4; ++mr)
#pragma unroll
        for (int nc = 0; nc < 4; ++nc) acc[mr][nc] = zero;

#pragma unroll
    for (int i = 0; i < 4; ++i) {
        gload_lds16(gA[i], lA[i]);
        gload_lds16(gB[i], lB[i]);
    }

    int cur = 0;
    for (int k0 = 0; k0 < K; k0 += 64) {
        int nxt = cur ^ 1;
        if (k0 + 64 < K) {
#pragma unroll
            for (int i = 0; i < 4; ++i) {
                gload_lds16(gA[i] + k0 + 64, lA[i] + nxt * TILE_ELEMS);
                gload_lds16(gB[i] + k0 + 64, lB[i] + nxt * TILE_ELEMS);
            }
            asm volatile("s_waitcnt vmcnt(8)" ::: "memory");
        } else {
            asm volatile("s_waitcnt vmcnt(0)" ::: "memory");
        }
        __builtin_amdgcn_s_barrier();
        __builtin_amdgcn_sched_barrier(0);
        const bf16* la = &lda[cur * TILE_ELEMS];
        const bf16* lb = &ldb[cur * TILE_ELEMS];
#pragma unroll
        for (int ks = 0; ks < 2; ++ks) {
            bf16x8 af[4], bfr[4];
            int ca = (((ks * 4 + quad) ^ (col & 7)) * 8);
#pragma unroll
            for (int t = 0; t < 4; ++t) {
                af[t]  = *(const bf16x8*)&la[(wr * 64 + t * 16 + col) * 64 + ca];
                bfr[t] = *(const bf16x8*)&lb[(wc * 64 + t * 16 + col) * 64 + ca];
            }
#pragma unroll
            for (int mr = 0; mr < 4; ++mr)
#pragma unroll
                for (int nc = 0; nc < 4; ++nc)
                    acc[mr][nc] = __builtin_amdgcn_mfma_f32_16x16x32_bf16(
                        af[mr], bfr[nc], acc[mr][nc], 0, 0, 0);
        }
        __builtin_amdgcn_sched_barrier(0);
        __builtin_amdgcn_s_barrier();
        cur = nxt;
    }

#pragma unroll
    for (int nc = 0; nc < 4; ++nc) {
        int n = n0 + wc * 64 + nc * 16 + col;
        float bv = bias[n];
#pragma unroll
        for (int mr = 0; mr < 4; ++mr) {
#pragma unroll
            for (int r = 0; r < 4; ++r) {
                int row = m0 + wr * 64 + mr * 16 + quad * 4 + r;
                Cmat[(size_t)row * N + n] = acc[mr][nc][r] + bv;
            }
        }
    }
}

// ---------------------------------------------------------------------------
// Fused causal flash attention — EXACT r10 structure (57.3-58.3us measured):
// 1024 blocks / 256 thr / 4 waves, T14 prefetch, P-in-register permuted-k
// PV, k-permuted V store, f32x4 lsum chains, heavy-first, T5 setprio.
// ---------------------------------------------------------------------------
__global__ __launch_bounds__(256) void attn_kernel(const bf16* __restrict__ qkv,
                                                   const bf16* __restrict__ Vt,
                                                   bf16* __restrict__ y,
                                                   int nGroups) {
    __shared__ bf16 ldsK[64 * KSTR];
    __shared__ bf16 ldsV[96 * VSTR];
    const int bid  = blockIdx.x;
    const int qt   = 31 - bid / nGroups;      // heavy blocks first
    const int g    = bid % nGroups;
    const int h    = g & 7, b = g >> 3;
    const int tid  = threadIdx.x;
    const int w    = tid >> 6, lane = tid & 63;
    const int col  = lane & 15, quad = lane >> 4;
    const float SCALE2 = 0.10206207261596577f * 1.4426950408889634f; // scale*log2e
    const float M0 = 24.0f;                    // static exponent shift (exact)
    const f32x4 zero = {0.f, 0.f, 0.f, 0.f};

    const bf16* qkvb = qkv + (size_t)b * T_ * QKN_;
    const bf16* Vtbh = Vt + (size_t)(b * H_ + h) * HS_ * T_;
    bf16* yb  = y + (size_t)b * T_ * C_;

    const int rbase = qt * 64 + w * 16;

    bf16x8 qf[3];
#pragma unroll
    for (int c = 0; c < 3; ++c)
        qf[c] = *(const bf16x8*)&qkvb[(size_t)(rbase + col) * QKN_ + h * HS_ + c * 32 + quad * 8];

    const bf16* pK[3]; const bf16* pV[3];
    bf16 *dK[3], *dV[3];
#pragma unroll
    for (int i = 0; i < 3; ++i) {
        int chunk = i * 256 + tid;
        int rK = chunk / 12, cK = chunk - rK * 12;
        pK[i] = qkvb + (size_t)rK * QKN_ + C_ + h * HS_ + cK * 8;
        dK[i] = &ldsK[rK * KSTR + cK * 8];
        int rV = chunk >> 3, cV = chunk & 7;
        pV[i] = Vtbh + (size_t)rV * T_ + cV * 8;
        dV[i] = &ldsV[rV * VSTR + cV * 8];
    }

    f32x4 o[6];
#pragma unroll
    for (int n2 = 0; n2 < 6; ++n2) o[n2] = zero;
    f32x4 lsum4 = zero;

    // prologue: prefetch jt=0 K/V into registers
    bf16x8 kreg[3], vreg[3];
#pragma unroll
    for (int i = 0; i < 3; ++i) {
        kreg[i] = *(const bf16x8*)pK[i];
        vreg[i] = *(const bf16x8*)pV[i];
        pK[i] += (size_t)64 * QKN_;
        pV[i] += 64;
    }

    const int njt = qt + 1;
    for (int jt = 0; jt < njt; ++jt) {
        int jb = jt * 64;
        __syncthreads();
        // write-late: regs -> LDS
#pragma unroll
        for (int i = 0; i < 3; ++i) {
            *(bf16x8*)dK[i] = kreg[i];
            *(bf16x8*)dV[i] = vreg[i];
        }
        __syncthreads();
        // issue-early: next tile's global loads fly under compute below
        if (jt + 1 < njt) {
#pragma unroll
            for (int i = 0; i < 3; ++i) {
                kreg[i] = *(const bf16x8*)pK[i];
                vreg[i] = *(const bf16x8*)pV[i];
                pK[i] += (size_t)64 * QKN_;
                pV[i] += 64;
            }
        }

        // QK^T: kf loaded per-nb (short live-range); T5 boost for MFMA cluster
        f32x4 st[4];
        __builtin_amdgcn_s_setprio(1);
#pragma unroll
        for (int nb = 0; nb < 4; ++nb) {
            st[nb] = zero;
#pragma unroll
            for (int c = 0; c < 3; ++c) {
                bf16x8 kf = *(const bf16x8*)&ldsK[(nb * 16 + col) * KSTR + c * 32 + quad * 8];
                st[nb] = __builtin_amdgcn_mfma_f32_16x16x32_bf16(
                    kf, qf[c], st[nb], 0, 0, 0);
            }
        }
        __builtin_amdgcn_s_setprio(0);

        if (jt == njt - 1) {
#pragma unroll
            for (int nb = 0; nb < 4; ++nb)
#pragma unroll
                for (int r = 0; r < 4; ++r) {
                    int jg = jb + nb * 16 + quad * 4 + r;
                    st[nb][r] = (jg <= rbase + col) ? fmaf(st[nb][r], SCALE2, -M0)
                                                    : NEG_BIG;
                }
        } else {
#pragma unroll
            for (int nb = 0; nb < 4; ++nb)
#pragma unroll
                for (int r = 0; r < 4; ++r)
                    st[nb][r] = fmaf(st[nb][r], SCALE2, -M0);
        }

#pragma unroll
        for (int nb = 0; nb < 4; ++nb) {
#pragma unroll
            for (int r = 0; r < 4; ++r)
                st[nb][r] = exp2f(st[nb][r]);
            lsum4 += st[nb];              // 4 independent FP chains
        }

        // Pack P as permuted-k B-operands (st stays in registers):
        // palo slot quad*8+j <-> k = (j<4?0:2)*16 + quad*4 + (j&3)
        // pahi slot quad*8+j <-> k = (j<4?1:3)*16 + quad*4 + (j&3)
        bf16x8 palo, pahi;
#pragma unroll
        for (int r = 0; r < 4; ++r) {
            palo[r]     = (bf16)st[0][r];
            palo[4 + r] = (bf16)st[2][r];
            pahi[r]     = (bf16)st[1][r];
            pahi[4 + r] = (bf16)st[3][r];
        }

        // V is k-permuted in storage: matching operand = contiguous b128
        __builtin_amdgcn_s_setprio(1);
#pragma unroll
        for (int n2 = 0; n2 < 6; ++n2) {
            const bf16* vrow = &ldsV[(n2 * 16 + col) * VSTR];
            bf16x8 vlo = *(const bf16x8*)&vrow[quad * 8];
            bf16x8 vhi = *(const bf16x8*)&vrow[32 + quad * 8];
            o[n2] = __builtin_amdgcn_mfma_f32_16x16x32_bf16(vlo, palo, o[n2], 0, 0, 0);
            o[n2] = __builtin_amdgcn_mfma_f32_16x16x32_bf16(vhi, pahi, o[n2], 0, 0, 0);
        }
        __builtin_amdgcn_s_setprio(0);
    }

    float lsum = (lsum4[0] + lsum4[1]) + (lsum4[2] + lsum4[3]);
    lsum += __shfl_xor(lsum, 16, 64);
    lsum += __shfl_xor(lsum, 32, 64);
    float linv = 1.0f / lsum;
#pragma unroll
    for (int n2 = 0; n2 < 6; ++n2) {
        bf16x4 pk = {(bf16)(o[n2][0] * linv), (bf16)(o[n2][1] * linv),
                     (bf16)(o[n2][2] * linv), (bf16)(o[n2][3] * linv)};
        *(bf16x4*)&yb[(size_t)(rbase + col) * C_ + h * HS_ + n2 * 16 + quad * 4] = pk;
    }
}

// ---------------------------------------------------------------------------
extern "C" void kernel_launch(void* const* d_in, const int* in_sizes, int n_in,
                              void* d_out, int out_size, void* d_ws, size_t ws_size,
                              hipStream_t stream) {
    (void)in_sizes; (void)n_in;
    const float* x      = (const float*)d_in[0];
    const float* W_attn = (const float*)d_in[1];
    const float* b_attn = (const float*)d_in[2];
    const float* W_proj = (const float*)d_in[3];
    const float* b_proj = (const float*)d_in[4];
    float* out = (float*)d_out;

    size_t e_wta = (size_t)QKN_ * C_;
    size_t e_wtp = (size_t)C_ * C_;
    size_t a_qkv = e_wta + e_wtp;
    size_t a_vt  = a_qkv + (size_t)M_ * QKN_;
    size_t a_yb  = a_vt + (size_t)M_ * C_;
    size_t needA = (a_yb + (size_t)M_ * C_) * sizeof(bf16);   // 67.6 MB
    size_t b_qkv = e_wta + e_wtp;
    size_t b_vt  = b_qkv + (size_t)T_ * QKN_;
    size_t b_yb  = b_vt + (size_t)T_ * C_;
    size_t needB = (b_yb + (size_t)T_ * C_) * sizeof(bf16);   // 20.4 MB

    if (ws_size >= needA) {
        bf16* Wt_attn = (bf16*)d_ws;
        bf16* Wt_proj = (bf16*)d_ws + e_wta;
        bf16* qkv     = (bf16*)d_ws + a_qkv;
        bf16* Vt      = (bf16*)d_ws + a_vt;
        bf16* yb      = (bf16*)d_ws + a_yb;
        bf16* xb      = yb;  // alias (xb dead before attn writes yb)
        prep_kernel<<<dim3(CONV_BLKS + TA_BLKS + TP_BLKS), 256, 0, stream>>>(
            x, xb, W_attn, Wt_attn, W_proj, Wt_proj);
        gemm_qkv<<<dim3(QKN_ / 128, M_ / 128), 256, 0, stream>>>(
            xb, Wt_attn, b_attn, qkv, Vt, M_, QKN_, C_);
        attn_kernel<<<dim3(32 * H_ * B_), 256, 0, stream>>>(qkv, Vt, yb, H_ * B_);
        gemm_proj<<<dim3(C_ / 128, M_ / 128), 256, 0, stream>>>(
            yb, Wt_proj, b_proj, out, M_, C_, C_);
    } else if (ws_size >= needB) {
        bf16* Wt_attn = (bf16*)d_ws;
        bf16* Wt_proj = (bf16*)d_ws + e_wta;
        bf16* qkv     = (bf16*)d_ws + b_qkv;
        bf16* Vt      = (bf16*)d_ws + b_vt;
        bf16* yb      = (bf16*)d_ws + b_yb;
        bf16* xb      = yb;  // alias per-batch
        transpose_kernel<<<dim3(QKN_ / 32, C_ / 32), dim3(32, 8), 0, stream>>>(W_attn, Wt_attn, C_, QKN_);
        transpose_kernel<<<dim3(C_ / 32, C_ / 32), dim3(32, 8), 0, stream>>>(W_proj, Wt_proj, C_, C_);
        for (int b = 0; b < B_; ++b) {
            const float* xf = x + (size_t)b * T_ * C_;
            float* outb     = out + (size_t)b * T_ * C_;
            convert_bf16_kernel<<<dim3(T_ * C_ / 8 / 256), 256, 0, stream>>>(xf, xb, T_ * C_ / 8);
            gemm_qkv<<<dim3(QKN_ / 128, T_ / 128), 256, 0, stream>>>(
                xb, Wt_attn, b_attn, qkv, Vt, T_, QKN_, C_);
            attn_kernel<<<dim3(32 * H_), 256, 0, stream>>>(qkv, Vt, yb, H_);
            gemm_proj<<<dim3(C_ / 128, T_ / 128), 256, 0, stream>>>(
                yb, Wt_proj, b_proj, outb, T_, C_, C_);
        }
    } else {
        sentinel_kernel<<<(out_size + 255) / 256, 256, 0, stream>>>(out, out_size);
    }
}

// Round 15
// 208.589 us; speedup vs baseline: 1.0105x; 1.0105x over previous
//
#include <hip/hip_runtime.h>

typedef __bf16 bf16;
typedef __attribute__((ext_vector_type(4))) __bf16 bf16x4;
typedef __attribute__((ext_vector_type(8))) __bf16 bf16x8;
typedef __attribute__((ext_vector_type(4))) float f32x4;

#define B_   4
#define T_   2048
#define C_   768
#define H_   8
#define HS_  96
#define M_   (B_ * T_)      /* 8192 */
#define QKN_ (3 * C_)       /* 2304 */

#define NEG_BIG (-1e30f)

// LDS strides (elements) for attn tiles (known-good 57.3-58.3us config)
#define KSTR 104   /* 64x(96) K tile rows, padded 96->104 */
#define VSTR 72    /* 96x(64) Vt tile rows, padded 64->72 */

// ---------------------------------------------------------------------------
// async global->LDS, 16B per lane. LDS dest must be wave-uniform base;
// HW writes base + lane*16 (m104). Global addr is per-lane.
// ---------------------------------------------------------------------------
__device__ __forceinline__ void gload_lds16(const bf16* g, bf16* l) {
    __builtin_amdgcn_global_load_lds(
        (const __attribute__((address_space(1))) uint32_t*)g,
        (__attribute__((address_space(3))) uint32_t*)l,
        16, 0, 0);
}

__device__ __forceinline__ bf16x8 cvt8(f32x4 v0, f32x4 v1) {
    bf16x8 o;
#pragma unroll
    for (int i = 0; i < 4; ++i) { o[i] = (bf16)v0[i]; o[4 + i] = (bf16)v1[i]; }
    return o;
}

// ---------------------------------------------------------------------------
// Transpose + convert: W[R][Cn] (fp32) -> Wt[Cn][R] (bf16)  (path-B fallback)
// ---------------------------------------------------------------------------
__global__ void transpose_kernel(const float* __restrict__ W, bf16* __restrict__ Wt,
                                 int R, int Cn) {
    __shared__ bf16 tile[32][33];
    int tx = threadIdx.x, ty = threadIdx.y;
    int x  = blockIdx.x * 32 + tx;
    int y0 = blockIdx.y * 32;
#pragma unroll
    for (int j = 0; j < 32; j += 8)
        tile[ty + j][tx] = (bf16)W[(size_t)(y0 + ty + j) * Cn + x];
    __syncthreads();
    int y2 = blockIdx.x * 32;
    int x2 = y0 + tx;
#pragma unroll
    for (int j = 0; j < 32; j += 8)
        Wt[(size_t)(y2 + ty + j) * R + x2] = tile[tx][ty + j];
}

// ---------------------------------------------------------------------------
__global__ void sentinel_kernel(float* __restrict__ out, int n) {
    int i = blockIdx.x * 256 + threadIdx.x;
    if (i < n) out[i] = 12345.0f;
}

// ---------------------------------------------------------------------------
// One-shot fp32 -> bf16 convert (x -> xb)  (path-B fallback)
// ---------------------------------------------------------------------------
__global__ __launch_bounds__(256) void convert_bf16_kernel(const float* __restrict__ in,
                                                           bf16* __restrict__ out,
                                                           int n8) {
    int i = blockIdx.x * 256 + threadIdx.x;
    if (i >= n8) return;
    const float* p = in + (size_t)i * 8;
    f32x4 a = *(const f32x4*)p;
    f32x4 b = *(const f32x4*)(p + 4);
    *(bf16x8*)&out[(size_t)i * 8] = cvt8(a, b);
}

// ---------------------------------------------------------------------------
// Merged prep: convert x->xb (bf16) + transpose both weights, one launch.
// ---------------------------------------------------------------------------
#define CONV_BLKS (M_ * C_ / 8 / 256)          /* 3072 */
#define TA_BX (QKN_ / 32)                      /* 72 */
#define TA_BLKS (TA_BX * (C_ / 32))            /* 1728 */
#define TP_BX (C_ / 32)                        /* 24 */
#define TP_BLKS (TP_BX * (C_ / 32))            /* 576 */

__device__ __forceinline__ void transpose_body(bf16 (*tile)[33],
                                               const float* __restrict__ W,
                                               bf16* __restrict__ Wt,
                                               int R, int Cn, int bx, int by, int tid) {
    int tx = tid & 31, ty = tid >> 5;
    int x  = bx * 32 + tx;
    int y0 = by * 32;
#pragma unroll
    for (int j = 0; j < 32; j += 8)
        tile[ty + j][tx] = (bf16)W[(size_t)(y0 + ty + j) * Cn + x];
    __syncthreads();
    int y2 = bx * 32;
    int x2 = y0 + tx;
#pragma unroll
    for (int j = 0; j < 32; j += 8)
        Wt[(size_t)(y2 + ty + j) * R + x2] = tile[tx][ty + j];
}

__global__ __launch_bounds__(256) void prep_kernel(const float* __restrict__ x,
                                                   bf16* __restrict__ xb,
                                                   const float* __restrict__ Wa,
                                                   bf16* __restrict__ Wta,
                                                   const float* __restrict__ Wp,
                                                   bf16* __restrict__ Wtp) {
    __shared__ bf16 tile[32][33];
    int bid = blockIdx.x;
    int tid = threadIdx.x;
    if (bid < CONV_BLKS) {
        int i = bid * 256 + tid;
        const float* p = x + (size_t)i * 8;
        f32x4 a = *(const f32x4*)p;
        f32x4 b = *(const f32x4*)(p + 4);
        *(bf16x8*)&xb[(size_t)i * 8] = cvt8(a, b);
    } else if (bid < CONV_BLKS + TA_BLKS) {
        int t = bid - CONV_BLKS;
        transpose_body(tile, Wa, Wta, C_, QKN_, t % TA_BX, t / TA_BX, tid);
    } else {
        int t = bid - CONV_BLKS - TA_BLKS;
        transpose_body(tile, Wp, Wtp, C_, C_, t % TP_BX, t / TP_BX, tid);
    }
}

#define TILE_ELEMS (128 * 64)

// ---------------------------------------------------------------------------
// GEMM1 — r10-exact (best measured): BK=64 double-buffer, counted vmcnt(8)
// (T4: prefetched tile's 8 loads stay in flight across the whole next
// iteration), source-side XOR chunk swizzle (T2), raw s_barrier pairs.
// BK=32 variant (r14) was conflict-free but barrier-bound: 63.6us vs ~55.
// Vt epilogue k-permutes t within each 64-tile (attn PV reads contiguous).
// ---------------------------------------------------------------------------
__global__ __launch_bounds__(256) void gemm_qkv(const bf16* __restrict__ A,
                                                const bf16* __restrict__ Bt,
                                                const float* __restrict__ bias,
                                                bf16* __restrict__ Cmat,
                                                bf16* __restrict__ Vt,
                                                int M, int N, int K) {
    __shared__ bf16 lda[2 * TILE_ELEMS];
    __shared__ bf16 ldb[2 * TILE_ELEMS];
    int tid  = threadIdx.x;
    int w    = tid >> 6;
    int lane = tid & 63;
    int col  = lane & 15, quad = lane >> 4;
    int wr   = w >> 1, wc = w & 1;
    int m0   = blockIdx.y * 128, n0 = blockIdx.x * 128;

    // staging: wave w owns segments w*4..w*4+3 (8 rows x 64 cols each).
    // Lane l -> row seg*8+(l>>3); SOURCE chunk (l&7)^srow (XOR swizzle);
    // LDS dest linear seg*1024B + l*16B (slot chunk l&7).
    int srow = lane >> 3;
    int scol = ((lane & 7) ^ srow) * 8;
    const bf16* gA[4]; const bf16* gB[4]; bf16* lA[4]; bf16* lB[4];
#pragma unroll
    for (int i = 0; i < 4; ++i) {
        int seg = w * 4 + i;
        int row = seg * 8 + srow;
        gA[i] = &A[(size_t)(m0 + row) * K + scol];
        gB[i] = &Bt[(size_t)(n0 + row) * K + scol];
        lA[i] = &lda[seg * 512];
        lB[i] = &ldb[seg * 512];
    }

    const f32x4 zero = {0.f, 0.f, 0.f, 0.f};
    f32x4 acc[4][4];
#pragma unroll
    for (int mr = 0; mr < 4; ++mr)
#pragma unroll
        for (int nc = 0; nc < 4; ++nc) acc[mr][nc] = zero;

    // prologue: stage tile 0 into buffer 0 (8 loads in flight, NOT drained)
#pragma unroll
    for (int i = 0; i < 4; ++i) {
        gload_lds16(gA[i], lA[i]);
        gload_lds16(gB[i], lB[i]);
    }

    int cur = 0;
    for (int k0 = 0; k0 < K; k0 += 64) {
        int nxt = cur ^ 1;
        if (k0 + 64 < K) {
            // issue next tile first; counted wait leaves those 8 in flight
#pragma unroll
            for (int i = 0; i < 4; ++i) {
                gload_lds16(gA[i] + k0 + 64, lA[i] + nxt * TILE_ELEMS);
                gload_lds16(gB[i] + k0 + 64, lB[i] + nxt * TILE_ELEMS);
            }
            asm volatile("s_waitcnt vmcnt(8)" ::: "memory");
        } else {
            asm volatile("s_waitcnt vmcnt(0)" ::: "memory");
        }
        __builtin_amdgcn_s_barrier();        // tile t landed for all waves
        __builtin_amdgcn_sched_barrier(0);   // no ds_read hoists above
        const bf16* la = &lda[cur * TILE_ELEMS];
        const bf16* lb = &ldb[cur * TILE_ELEMS];
#pragma unroll
        for (int ks = 0; ks < 2; ++ks) {
            bf16x8 af[4], bfr[4];
            int ca = (((ks * 4 + quad) ^ (col & 7)) * 8);  // swizzled chunk
#pragma unroll
            for (int t = 0; t < 4; ++t) {
                af[t]  = *(const bf16x8*)&la[(wr * 64 + t * 16 + col) * 64 + ca];
                bfr[t] = *(const bf16x8*)&lb[(wc * 64 + t * 16 + col) * 64 + ca];
            }
#pragma unroll
            for (int mr = 0; mr < 4; ++mr)
#pragma unroll
                for (int nc = 0; nc < 4; ++nc)
                    acc[mr][nc] = __builtin_amdgcn_mfma_f32_16x16x32_bf16(
                        af[mr], bfr[nc], acc[mr][nc], 0, 0, 0);
        }
        __builtin_amdgcn_sched_barrier(0);   // reads stay above the barrier
        __builtin_amdgcn_s_barrier();        // reads done before overwrite
        cur = nxt;
    }

#pragma unroll
    for (int nc = 0; nc < 4; ++nc) {
        int n = n0 + wc * 64 + nc * 16 + col;
        float bv = bias[n];
#pragma unroll
        for (int mr = 0; mr < 4; ++mr) {
#pragma unroll
            for (int r = 0; r < 4; ++r) {
                int row = m0 + wr * 64 + mr * 16 + quad * 4 + r;
                Cmat[(size_t)row * N + n] = (bf16)(acc[mr][nc][r] + bv);
            }
        }
    }
    if (n0 >= 2 * C_) {
        int batch = m0 >> 11;
        bf16* Vtb = Vt + (size_t)batch * C_ * T_;
        int t0 = (m0 & 2047) + wr * 64;
#pragma unroll
        for (int nc = 0; nc < 4; ++nc) {
            int n  = n0 + wc * 64 + nc * 16 + col;
            int vc = n - 2 * C_;
            float bv = bias[n];
#pragma unroll
            for (int mr = 0; mr < 4; ++mr) {
                int t  = t0 + mr * 16 + quad * 4;
                int tb = t & ~63;                 // 64-tile base
                int a  = (t >> 2) & 15;           // 4-chunk index in tile
                int ts = tb + ((a & 7) << 3) + ((a >> 3) << 2);  // permuted base
                bf16x4 pk = {(bf16)(acc[mr][nc][0] + bv), (bf16)(acc[mr][nc][1] + bv),
                             (bf16)(acc[mr][nc][2] + bv), (bf16)(acc[mr][nc][3] + bv)};
                *(bf16x4*)&Vtb[(size_t)vc * T_ + ts] = pk;
            }
        }
    }
}

// ---------------------------------------------------------------------------
// GEMM2 — r10-exact (128x128, counted vmcnt(8), XOR swizzle).
// ---------------------------------------------------------------------------
__global__ __launch_bounds__(256) void gemm_proj(const bf16* __restrict__ A,
                                                 const bf16* __restrict__ Bt,
                                                 const float* __restrict__ bias,
                                                 float* __restrict__ Cmat,
                                                 int M, int N, int K) {
    __shared__ bf16 lda[2 * TILE_ELEMS];
    __shared__ bf16 ldb[2 * TILE_ELEMS];
    int tid  = threadIdx.x;
    int w    = tid >> 6;
    int lane = tid & 63;
    int col  = lane & 15, quad = lane >> 4;
    int wr   = w >> 1, wc = w & 1;
    int m0   = blockIdx.y * 128, n0 = blockIdx.x * 128;

    int srow = lane >> 3;
    int scol = ((lane & 7) ^ srow) * 8;
    const bf16* gA[4]; const bf16* gB[4]; bf16* lA[4]; bf16* lB[4];
#pragma unroll
    for (int i = 0; i < 4; ++i) {
        int seg = w * 4 + i;
        int row = seg * 8 + srow;
        gA[i] = &A[(size_t)(m0 + row) * K + scol];
        gB[i] = &Bt[(size_t)(n0 + row) * K + scol];
        lA[i] = &lda[seg * 512];
        lB[i] = &ldb[seg * 512];
    }

    const f32x4 zero = {0.f, 0.f, 0.f, 0.f};
    f32x4 acc[4][4];
#pragma unroll
    for (int mr = 0; mr < 4; ++mr)
#pragma unroll
        for (int nc = 0; nc < 4; ++nc) acc[mr][nc] = zero;

#pragma unroll
    for (int i = 0; i < 4; ++i) {
        gload_lds16(gA[i], lA[i]);
        gload_lds16(gB[i], lB[i]);
    }

    int cur = 0;
    for (int k0 = 0; k0 < K; k0 += 64) {
        int nxt = cur ^ 1;
        if (k0 + 64 < K) {
#pragma unroll
            for (int i = 0; i < 4; ++i) {
                gload_lds16(gA[i] + k0 + 64, lA[i] + nxt * TILE_ELEMS);
                gload_lds16(gB[i] + k0 + 64, lB[i] + nxt * TILE_ELEMS);
            }
            asm volatile("s_waitcnt vmcnt(8)" ::: "memory");
        } else {
            asm volatile("s_waitcnt vmcnt(0)" ::: "memory");
        }
        __builtin_amdgcn_s_barrier();
        __builtin_amdgcn_sched_barrier(0);
        const bf16* la = &lda[cur * TILE_ELEMS];
        const bf16* lb = &ldb[cur * TILE_ELEMS];
#pragma unroll
        for (int ks = 0; ks < 2; ++ks) {
            bf16x8 af[4], bfr[4];
            int ca = (((ks * 4 + quad) ^ (col & 7)) * 8);
#pragma unroll
            for (int t = 0; t < 4; ++t) {
                af[t]  = *(const bf16x8*)&la[(wr * 64 + t * 16 + col) * 64 + ca];
                bfr[t] = *(const bf16x8*)&lb[(wc * 64 + t * 16 + col) * 64 + ca];
            }
#pragma unroll
            for (int mr = 0; mr < 4; ++mr)
#pragma unroll
                for (int nc = 0; nc < 4; ++nc)
                    acc[mr][nc] = __builtin_amdgcn_mfma_f32_16x16x32_bf16(
                        af[mr], bfr[nc], acc[mr][nc], 0, 0, 0);
        }
        __builtin_amdgcn_sched_barrier(0);
        __builtin_amdgcn_s_barrier();
        cur = nxt;
    }

#pragma unroll
    for (int nc = 0; nc < 4; ++nc) {
        int n = n0 + wc * 64 + nc * 16 + col;
        float bv = bias[n];
#pragma unroll
        for (int mr = 0; mr < 4; ++mr) {
#pragma unroll
            for (int r = 0; r < 4; ++r) {
                int row = m0 + wr * 64 + mr * 16 + quad * 4 + r;
                Cmat[(size_t)row * N + n] = acc[mr][nc][r] + bv;
            }
        }
    }
}

// ---------------------------------------------------------------------------
// Fused causal flash attention — r10-exact (57.3-58.3us measured):
// 1024 blocks / 256 thr / 4 waves, T14 prefetch, P-in-register permuted-k
// PV, k-permuted V store, f32x4 lsum chains, heavy-first, T5 setprio.
// ---------------------------------------------------------------------------
__global__ __launch_bounds__(256) void attn_kernel(const bf16* __restrict__ qkv,
                                                   const bf16* __restrict__ Vt,
                                                   bf16* __restrict__ y,
                                                   int nGroups) {
    __shared__ bf16 ldsK[64 * KSTR];
    __shared__ bf16 ldsV[96 * VSTR];
    const int bid  = blockIdx.x;
    const int qt   = 31 - bid / nGroups;      // heavy blocks first
    const int g    = bid % nGroups;
    const int h    = g & 7, b = g >> 3;
    const int tid  = threadIdx.x;
    const int w    = tid >> 6, lane = tid & 63;
    const int col  = lane & 15, quad = lane >> 4;
    const float SCALE2 = 0.10206207261596577f * 1.4426950408889634f; // scale*log2e
    const float M0 = 24.0f;                    // static exponent shift (exact)
    const f32x4 zero = {0.f, 0.f, 0.f, 0.f};

    const bf16* qkvb = qkv + (size_t)b * T_ * QKN_;
    const bf16* Vtbh = Vt + (size_t)(b * H_ + h) * HS_ * T_;
    bf16* yb  = y + (size_t)b * T_ * C_;

    const int rbase = qt * 64 + w * 16;

    bf16x8 qf[3];
#pragma unroll
    for (int c = 0; c < 3; ++c)
        qf[c] = *(const bf16x8*)&qkvb[(size_t)(rbase + col) * QKN_ + h * HS_ + c * 32 + quad * 8];

    const bf16* pK[3]; const bf16* pV[3];
    bf16 *dK[3], *dV[3];
#pragma unroll
    for (int i = 0; i < 3; ++i) {
        int chunk = i * 256 + tid;
        int rK = chunk / 12, cK = chunk - rK * 12;
        pK[i] = qkvb + (size_t)rK * QKN_ + C_ + h * HS_ + cK * 8;
        dK[i] = &ldsK[rK * KSTR + cK * 8];
        int rV = chunk >> 3, cV = chunk & 7;
        pV[i] = Vtbh + (size_t)rV * T_ + cV * 8;
        dV[i] = &ldsV[rV * VSTR + cV * 8];
    }

    f32x4 o[6];
#pragma unroll
    for (int n2 = 0; n2 < 6; ++n2) o[n2] = zero;
    f32x4 lsum4 = zero;

    // prologue: prefetch jt=0 K/V into registers
    bf16x8 kreg[3], vreg[3];
#pragma unroll
    for (int i = 0; i < 3; ++i) {
        kreg[i] = *(const bf16x8*)pK[i];
        vreg[i] = *(const bf16x8*)pV[i];
        pK[i] += (size_t)64 * QKN_;
        pV[i] += 64;
    }

    const int njt = qt + 1;
    for (int jt = 0; jt < njt; ++jt) {
        int jb = jt * 64;
        __syncthreads();
        // write-late: regs -> LDS
#pragma unroll
        for (int i = 0; i < 3; ++i) {
            *(bf16x8*)dK[i] = kreg[i];
            *(bf16x8*)dV[i] = vreg[i];
        }
        __syncthreads();
        // issue-early: next tile's global loads fly under compute below
        if (jt + 1 < njt) {
#pragma unroll
            for (int i = 0; i < 3; ++i) {
                kreg[i] = *(const bf16x8*)pK[i];
                vreg[i] = *(const bf16x8*)pV[i];
                pK[i] += (size_t)64 * QKN_;
                pV[i] += 64;
            }
        }

        // QK^T: kf loaded per-nb (short live-range); T5 boost for MFMA cluster
        f32x4 st[4];
        __builtin_amdgcn_s_setprio(1);
#pragma unroll
        for (int nb = 0; nb < 4; ++nb) {
            st[nb] = zero;
#pragma unroll
            for (int c = 0; c < 3; ++c) {
                bf16x8 kf = *(const bf16x8*)&ldsK[(nb * 16 + col) * KSTR + c * 32 + quad * 8];
                st[nb] = __builtin_amdgcn_mfma_f32_16x16x32_bf16(
                    kf, qf[c], st[nb], 0, 0, 0);
            }
        }
        __builtin_amdgcn_s_setprio(0);

        if (jt == njt - 1) {
#pragma unroll
            for (int nb = 0; nb < 4; ++nb)
#pragma unroll
                for (int r = 0; r < 4; ++r) {
                    int jg = jb + nb * 16 + quad * 4 + r;
                    st[nb][r] = (jg <= rbase + col) ? fmaf(st[nb][r], SCALE2, -M0)
                                                    : NEG_BIG;
                }
        } else {
#pragma unroll
            for (int nb = 0; nb < 4; ++nb)
#pragma unroll
                for (int r = 0; r < 4; ++r)
                    st[nb][r] = fmaf(st[nb][r], SCALE2, -M0);
        }

#pragma unroll
        for (int nb = 0; nb < 4; ++nb) {
#pragma unroll
            for (int r = 0; r < 4; ++r)
                st[nb][r] = exp2f(st[nb][r]);
            lsum4 += st[nb];              // 4 independent FP chains
        }

        // Pack P as permuted-k B-operands (st stays in registers):
        // palo slot quad*8+j <-> k = (j<4?0:2)*16 + quad*4 + (j&3)
        // pahi slot quad*8+j <-> k = (j<4?1:3)*16 + quad*4 + (j&3)
        bf16x8 palo, pahi;
#pragma unroll
        for (int r = 0; r < 4; ++r) {
            palo[r]     = (bf16)st[0][r];
            palo[4 + r] = (bf16)st[2][r];
            pahi[r]     = (bf16)st[1][r];
            pahi[4 + r] = (bf16)st[3][r];
        }

        // V is k-permuted in storage: matching operand = contiguous b128
        __builtin_amdgcn_s_setprio(1);
#pragma unroll
        for (int n2 = 0; n2 < 6; ++n2) {
            const bf16* vrow = &ldsV[(n2 * 16 + col) * VSTR];
            bf16x8 vlo = *(const bf16x8*)&vrow[quad * 8];
            bf16x8 vhi = *(const bf16x8*)&vrow[32 + quad * 8];
            o[n2] = __builtin_amdgcn_mfma_f32_16x16x32_bf16(vlo, palo, o[n2], 0, 0, 0);
            o[n2] = __builtin_amdgcn_mfma_f32_16x16x32_bf16(vhi, pahi, o[n2], 0, 0, 0);
        }
        __builtin_amdgcn_s_setprio(0);
    }

    float lsum = (lsum4[0] + lsum4[1]) + (lsum4[2] + lsum4[3]);
    lsum += __shfl_xor(lsum, 16, 64);
    lsum += __shfl_xor(lsum, 32, 64);
    float linv = 1.0f / lsum;
#pragma unroll
    for (int n2 = 0; n2 < 6; ++n2) {
        bf16x4 pk = {(bf16)(o[n2][0] * linv), (bf16)(o[n2][1] * linv),
                     (bf16)(o[n2][2] * linv), (bf16)(o[n2][3] * linv)};
        *(bf16x4*)&yb[(size_t)(rbase + col) * C_ + h * HS_ + n2 * 16 + quad * 4] = pk;
    }
}

// ---------------------------------------------------------------------------
extern "C" void kernel_launch(void* const* d_in, const int* in_sizes, int n_in,
                              void* d_out, int out_size, void* d_ws, size_t ws_size,
                              hipStream_t stream) {
    (void)in_sizes; (void)n_in;
    const float* x      = (const float*)d_in[0];
    const float* W_attn = (const float*)d_in[1];
    const float* b_attn = (const float*)d_in[2];
    const float* W_proj = (const float*)d_in[3];
    const float* b_proj = (const float*)d_in[4];
    float* out = (float*)d_out;

    size_t e_wta = (size_t)QKN_ * C_;
    size_t e_wtp = (size_t)C_ * C_;
    size_t a_qkv = e_wta + e_wtp;
    size_t a_vt  = a_qkv + (size_t)M_ * QKN_;
    size_t a_yb  = a_vt + (size_t)M_ * C_;
    size_t needA = (a_yb + (size_t)M_ * C_) * sizeof(bf16);   // 67.6 MB
    size_t b_qkv = e_wta + e_wtp;
    size_t b_vt  = b_qkv + (size_t)T_ * QKN_;
    size_t b_yb  = b_vt + (size_t)T_ * C_;
    size_t needB = (b_yb + (size_t)T_ * C_) * sizeof(bf16);   // 20.4 MB

    if (ws_size >= needA) {
        bf16* Wt_attn = (bf16*)d_ws;
        bf16* Wt_proj = (bf16*)d_ws + e_wta;
        bf16* qkv     = (bf16*)d_ws + a_qkv;
        bf16* Vt      = (bf16*)d_ws + a_vt;
        bf16* yb      = (bf16*)d_ws + a_yb;
        bf16* xb      = yb;  // alias (xb dead before attn writes yb)
        prep_kernel<<<dim3(CONV_BLKS + TA_BLKS + TP_BLKS), 256, 0, stream>>>(
            x, xb, W_attn, Wt_attn, W_proj, Wt_proj);
        gemm_qkv<<<dim3(QKN_ / 128, M_ / 128), 256, 0, stream>>>(
            xb, Wt_attn, b_attn, qkv, Vt, M_, QKN_, C_);
        attn_kernel<<<dim3(32 * H_ * B_), 256, 0, stream>>>(qkv, Vt, yb, H_ * B_);
        gemm_proj<<<dim3(C_ / 128, M_ / 128), 256, 0, stream>>>(
            yb, Wt_proj, b_proj, out, M_, C_, C_);
    } else if (ws_size >= needB) {
        bf16* Wt_attn = (bf16*)d_ws;
        bf16* Wt_proj = (bf16*)d_ws + e_wta;
        bf16* qkv     = (bf16*)d_ws + b_qkv;
        bf16* Vt      = (bf16*)d_ws + b_vt;
        bf16* yb      = (bf16*)d_ws + b_yb;
        bf16* xb      = yb;  // alias per-batch
        transpose_kernel<<<dim3(QKN_ / 32, C_ / 32), dim3(32, 8), 0, stream>>>(W_attn, Wt_attn, C_, QKN_);
        transpose_kernel<<<dim3(C_ / 32, C_ / 32), dim3(32, 8), 0, stream>>>(W_proj, Wt_proj, C_, C_);
        for (int b = 0; b < B_; ++b) {
            const float* xf = x + (size_t)b * T_ * C_;
            float* outb     = out + (size_t)b * T_ * C_;
            convert_bf16_kernel<<<dim3(T_ * C_ / 8 / 256), 256, 0, stream>>>(xf, xb, T_ * C_ / 8);
            gemm_qkv<<<dim3(QKN_ / 128, T_ / 128), 256, 0, stream>>>(
                xb, Wt_attn, b_attn, qkv, Vt, T_, QKN_, C_);
            attn_kernel<<<dim3(32 * H_), 256, 0, stream>>>(qkv, Vt, yb, H_);
            gemm_proj<<<dim3(C_ / 128, T_ / 128), 256, 0, stream>>>(
                yb, Wt_proj, b_proj, outb, T_, C_, C_);
        }
    } else {
        sentinel_kernel<<<(out_size + 255) / 256, 256, 0, stream>>>(out, out_size);
    }
}

// Round 16
// 201.234 us; speedup vs baseline: 1.0475x; 1.0365x over previous
//
#include <hip/hip_runtime.h>

typedef __bf16 bf16;
typedef __attribute__((ext_vector_type(4))) __bf16 bf16x4;
typedef __attribute__((ext_vector_type(8))) __bf16 bf16x8;
typedef __attribute__((ext_vector_type(4))) float f32x4;

#define B_   4
#define T_   2048
#define C_   768
#define H_   8
#define HS_  96
#define M_   (B_ * T_)      /* 8192 */
#define QKN_ (3 * C_)       /* 2304 */

#define NEG_BIG (-1e30f)

// LDS strides (elements) for attn tiles (known-good 57.3-58.3us config)
#define KSTR 104   /* 64x(96) K tile rows, padded 96->104 */
#define VSTR 72    /* 96x(64) Vt tile rows, padded 64->72 */

// ---------------------------------------------------------------------------
// async global->LDS, 16B per lane. LDS dest must be wave-uniform base;
// HW writes base + lane*16 (m104). Global addr is per-lane.
// ---------------------------------------------------------------------------
__device__ __forceinline__ void gload_lds16(const bf16* g, bf16* l) {
    __builtin_amdgcn_global_load_lds(
        (const __attribute__((address_space(1))) uint32_t*)g,
        (__attribute__((address_space(3))) uint32_t*)l,
        16, 0, 0);
}

__device__ __forceinline__ bf16x8 cvt8(f32x4 v0, f32x4 v1) {
    bf16x8 o;
#pragma unroll
    for (int i = 0; i < 4; ++i) { o[i] = (bf16)v0[i]; o[4 + i] = (bf16)v1[i]; }
    return o;
}

// ---------------------------------------------------------------------------
// Transpose + convert: W[R][Cn] (fp32) -> Wt[Cn][R] (bf16)  (path-B fallback)
// ---------------------------------------------------------------------------
__global__ void transpose_kernel(const float* __restrict__ W, bf16* __restrict__ Wt,
                                 int R, int Cn) {
    __shared__ bf16 tile[32][33];
    int tx = threadIdx.x, ty = threadIdx.y;
    int x  = blockIdx.x * 32 + tx;
    int y0 = blockIdx.y * 32;
#pragma unroll
    for (int j = 0; j < 32; j += 8)
        tile[ty + j][tx] = (bf16)W[(size_t)(y0 + ty + j) * Cn + x];
    __syncthreads();
    int y2 = blockIdx.x * 32;
    int x2 = y0 + tx;
#pragma unroll
    for (int j = 0; j < 32; j += 8)
        Wt[(size_t)(y2 + ty + j) * R + x2] = tile[tx][ty + j];
}

// ---------------------------------------------------------------------------
__global__ void sentinel_kernel(float* __restrict__ out, int n) {
    int i = blockIdx.x * 256 + threadIdx.x;
    if (i < n) out[i] = 12345.0f;
}

// ---------------------------------------------------------------------------
// One-shot fp32 -> bf16 convert (x -> xb)  (path-B fallback)
// ---------------------------------------------------------------------------
__global__ __launch_bounds__(256) void convert_bf16_kernel(const float* __restrict__ in,
                                                           bf16* __restrict__ out,
                                                           int n8) {
    int i = blockIdx.x * 256 + threadIdx.x;
    if (i >= n8) return;
    const float* p = in + (size_t)i * 8;
    f32x4 a = *(const f32x4*)p;
    f32x4 b = *(const f32x4*)(p + 4);
    *(bf16x8*)&out[(size_t)i * 8] = cvt8(a, b);
}

// ---------------------------------------------------------------------------
// Merged prep: convert x->xb (bf16) + transpose both weights, one launch.
// ---------------------------------------------------------------------------
#define CONV_BLKS (M_ * C_ / 8 / 256)          /* 3072 */
#define TA_BX (QKN_ / 32)                      /* 72 */
#define TA_BLKS (TA_BX * (C_ / 32))            /* 1728 */
#define TP_BX (C_ / 32)                        /* 24 */
#define TP_BLKS (TP_BX * (C_ / 32))            /* 576 */

__device__ __forceinline__ void transpose_body(bf16 (*tile)[33],
                                               const float* __restrict__ W,
                                               bf16* __restrict__ Wt,
                                               int R, int Cn, int bx, int by, int tid) {
    int tx = tid & 31, ty = tid >> 5;
    int x  = bx * 32 + tx;
    int y0 = by * 32;
#pragma unroll
    for (int j = 0; j < 32; j += 8)
        tile[ty + j][tx] = (bf16)W[(size_t)(y0 + ty + j) * Cn + x];
    __syncthreads();
    int y2 = bx * 32;
    int x2 = y0 + tx;
#pragma unroll
    for (int j = 0; j < 32; j += 8)
        Wt[(size_t)(y2 + ty + j) * R + x2] = tile[tx][ty + j];
}

__global__ __launch_bounds__(256) void prep_kernel(const float* __restrict__ x,
                                                   bf16* __restrict__ xb,
                                                   const float* __restrict__ Wa,
                                                   bf16* __restrict__ Wta,
                                                   const float* __restrict__ Wp,
                                                   bf16* __restrict__ Wtp) {
    __shared__ bf16 tile[32][33];
    int bid = blockIdx.x;
    int tid = threadIdx.x;
    if (bid < CONV_BLKS) {
        int i = bid * 256 + tid;
        const float* p = x + (size_t)i * 8;
        f32x4 a = *(const f32x4*)p;
        f32x4 b = *(const f32x4*)(p + 4);
        *(bf16x8*)&xb[(size_t)i * 8] = cvt8(a, b);
    } else if (bid < CONV_BLKS + TA_BLKS) {
        int t = bid - CONV_BLKS;
        transpose_body(tile, Wa, Wta, C_, QKN_, t % TA_BX, t / TA_BX, tid);
    } else {
        int t = bid - CONV_BLKS - TA_BLKS;
        transpose_body(tile, Wp, Wtp, C_, C_, t % TP_BX, t / TP_BX, tid);
    }
}

#define TILE_ELEMS (128 * 64)

// ---------------------------------------------------------------------------
// GEMM1 — r10-exact (best measured): BK=64 double-buffer, counted vmcnt(8),
// source-side XOR chunk swizzle, raw s_barrier pairs.
// Vt epilogue k-permutes t within each 64-tile (attn PV reads contiguous).
// ---------------------------------------------------------------------------
__global__ __launch_bounds__(256) void gemm_qkv(const bf16* __restrict__ A,
                                                const bf16* __restrict__ Bt,
                                                const float* __restrict__ bias,
                                                bf16* __restrict__ Cmat,
                                                bf16* __restrict__ Vt,
                                                int M, int N, int K) {
    __shared__ bf16 lda[2 * TILE_ELEMS];
    __shared__ bf16 ldb[2 * TILE_ELEMS];
    int tid  = threadIdx.x;
    int w    = tid >> 6;
    int lane = tid & 63;
    int col  = lane & 15, quad = lane >> 4;
    int wr   = w >> 1, wc = w & 1;
    int m0   = blockIdx.y * 128, n0 = blockIdx.x * 128;

    int srow = lane >> 3;
    int scol = ((lane & 7) ^ srow) * 8;
    const bf16* gA[4]; const bf16* gB[4]; bf16* lA[4]; bf16* lB[4];
#pragma unroll
    for (int i = 0; i < 4; ++i) {
        int seg = w * 4 + i;
        int row = seg * 8 + srow;
        gA[i] = &A[(size_t)(m0 + row) * K + scol];
        gB[i] = &Bt[(size_t)(n0 + row) * K + scol];
        lA[i] = &lda[seg * 512];
        lB[i] = &ldb[seg * 512];
    }

    const f32x4 zero = {0.f, 0.f, 0.f, 0.f};
    f32x4 acc[4][4];
#pragma unroll
    for (int mr = 0; mr < 4; ++mr)
#pragma unroll
        for (int nc = 0; nc < 4; ++nc) acc[mr][nc] = zero;

#pragma unroll
    for (int i = 0; i < 4; ++i) {
        gload_lds16(gA[i], lA[i]);
        gload_lds16(gB[i], lB[i]);
    }

    int cur = 0;
    for (int k0 = 0; k0 < K; k0 += 64) {
        int nxt = cur ^ 1;
        if (k0 + 64 < K) {
#pragma unroll
            for (int i = 0; i < 4; ++i) {
                gload_lds16(gA[i] + k0 + 64, lA[i] + nxt * TILE_ELEMS);
                gload_lds16(gB[i] + k0 + 64, lB[i] + nxt * TILE_ELEMS);
            }
            asm volatile("s_waitcnt vmcnt(8)" ::: "memory");
        } else {
            asm volatile("s_waitcnt vmcnt(0)" ::: "memory");
        }
        __builtin_amdgcn_s_barrier();
        __builtin_amdgcn_sched_barrier(0);
        const bf16* la = &lda[cur * TILE_ELEMS];
        const bf16* lb = &ldb[cur * TILE_ELEMS];
#pragma unroll
        for (int ks = 0; ks < 2; ++ks) {
            bf16x8 af[4], bfr[4];
            int ca = (((ks * 4 + quad) ^ (col & 7)) * 8);
#pragma unroll
            for (int t = 0; t < 4; ++t) {
                af[t]  = *(const bf16x8*)&la[(wr * 64 + t * 16 + col) * 64 + ca];
                bfr[t] = *(const bf16x8*)&lb[(wc * 64 + t * 16 + col) * 64 + ca];
            }
#pragma unroll
            for (int mr = 0; mr < 4; ++mr)
#pragma unroll
                for (int nc = 0; nc < 4; ++nc)
                    acc[mr][nc] = __builtin_amdgcn_mfma_f32_16x16x32_bf16(
                        af[mr], bfr[nc], acc[mr][nc], 0, 0, 0);
        }
        __builtin_amdgcn_sched_barrier(0);
        __builtin_amdgcn_s_barrier();
        cur = nxt;
    }

#pragma unroll
    for (int nc = 0; nc < 4; ++nc) {
        int n = n0 + wc * 64 + nc * 16 + col;
        float bv = bias[n];
#pragma unroll
        for (int mr = 0; mr < 4; ++mr) {
#pragma unroll
            for (int r = 0; r < 4; ++r) {
                int row = m0 + wr * 64 + mr * 16 + quad * 4 + r;
                Cmat[(size_t)row * N + n] = (bf16)(acc[mr][nc][r] + bv);
            }
        }
    }
    if (n0 >= 2 * C_) {
        int batch = m0 >> 11;
        bf16* Vtb = Vt + (size_t)batch * C_ * T_;
        int t0 = (m0 & 2047) + wr * 64;
#pragma unroll
        for (int nc = 0; nc < 4; ++nc) {
            int n  = n0 + wc * 64 + nc * 16 + col;
            int vc = n - 2 * C_;
            float bv = bias[n];
#pragma unroll
            for (int mr = 0; mr < 4; ++mr) {
                int t  = t0 + mr * 16 + quad * 4;
                int tb = t & ~63;                 // 64-tile base
                int a  = (t >> 2) & 15;           // 4-chunk index in tile
                int ts = tb + ((a & 7) << 3) + ((a >> 3) << 2);  // permuted base
                bf16x4 pk = {(bf16)(acc[mr][nc][0] + bv), (bf16)(acc[mr][nc][1] + bv),
                             (bf16)(acc[mr][nc][2] + bv), (bf16)(acc[mr][nc][3] + bv)};
                *(bf16x4*)&Vtb[(size_t)vc * T_ + ts] = pk;
            }
        }
    }
}

// ---------------------------------------------------------------------------
// GEMM2 r16: 128x96 tile -> grid 8x64 = 512 blocks = EXACTLY 2.0 blocks/CU
// (was 6x64 = 384 = 1.5/CU: makespan = 2 block-rounds, second half-empty;
// now 2 full rounds of 0.75x-sized blocks = ~25% faster makespan).
// Same counted-vmcnt(7) + XOR-swizzle loop; waves 2x2, each 64x48
// (acc[4][3], 7 ds_reads : 12 MFMA per K-half). LDS 56 KB = 2/CU.
// Asymmetric staging (A 4 segs/wave, B 3 segs/wave) per r12-validated pattern.
// ---------------------------------------------------------------------------
#define PJA_ELEMS (128 * 64)
#define PJB_ELEMS (96 * 64)
__global__ __launch_bounds__(256) void gemm_proj(const bf16* __restrict__ A,
                                                 const bf16* __restrict__ Bt,
                                                 const float* __restrict__ bias,
                                                 float* __restrict__ Cmat,
                                                 int M, int N, int K) {
    __shared__ bf16 lda[2 * PJA_ELEMS];
    __shared__ bf16 ldb[2 * PJB_ELEMS];
    int tid  = threadIdx.x;
    int w    = tid >> 6;
    int lane = tid & 63;
    int col  = lane & 15, quad = lane >> 4;
    int wr   = w >> 1, wc = w & 1;
    int m0   = blockIdx.y * 128, n0 = blockIdx.x * 96;

    int srow = lane >> 3;
    int scol = ((lane & 7) ^ srow) * 8;
    // A: 16 segs (8 rows x 64 cols); wave w stages segs w*4..w*4+3.
    // B: 12 segs; wave w stages segs w*3..w*3+2.  7 loads/wave in flight.
    const bf16* gA[4]; bf16* lA[4];
    const bf16* gB[3]; bf16* lB[3];
#pragma unroll
    for (int i = 0; i < 4; ++i) {
        int seg = w * 4 + i;
        int row = seg * 8 + srow;
        gA[i] = &A[(size_t)(m0 + row) * K + scol];
        lA[i] = &lda[seg * 512];
    }
#pragma unroll
    for (int i = 0; i < 3; ++i) {
        int seg = w * 3 + i;
        int row = seg * 8 + srow;
        gB[i] = &Bt[(size_t)(n0 + row) * K + scol];
        lB[i] = &ldb[seg * 512];
    }

    const f32x4 zero = {0.f, 0.f, 0.f, 0.f};
    f32x4 acc[4][3];
#pragma unroll
    for (int mr = 0; mr < 4; ++mr)
#pragma unroll
        for (int nc = 0; nc < 3; ++nc) acc[mr][nc] = zero;

#pragma unroll
    for (int i = 0; i < 4; ++i) gload_lds16(gA[i], lA[i]);
#pragma unroll
    for (int i = 0; i < 3; ++i) gload_lds16(gB[i], lB[i]);

    int cur = 0;
    for (int k0 = 0; k0 < K; k0 += 64) {
        int nxt = cur ^ 1;
        if (k0 + 64 < K) {
#pragma unroll
            for (int i = 0; i < 4; ++i)
                gload_lds16(gA[i] + k0 + 64, lA[i] + nxt * PJA_ELEMS);
#pragma unroll
            for (int i = 0; i < 3; ++i)
                gload_lds16(gB[i] + k0 + 64, lB[i] + nxt * PJB_ELEMS);
            asm volatile("s_waitcnt vmcnt(7)" ::: "memory");
        } else {
            asm volatile("s_waitcnt vmcnt(0)" ::: "memory");
        }
        __builtin_amdgcn_s_barrier();
        __builtin_amdgcn_sched_barrier(0);
        const bf16* la = &lda[cur * PJA_ELEMS];
        const bf16* lb = &ldb[cur * PJB_ELEMS];
#pragma unroll
        for (int ks = 0; ks < 2; ++ks) {
            bf16x8 af[4], bfr[3];
            int ca = (((ks * 4 + quad) ^ (col & 7)) * 8);
#pragma unroll
            for (int t = 0; t < 4; ++t)
                af[t]  = *(const bf16x8*)&la[(wr * 64 + t * 16 + col) * 64 + ca];
#pragma unroll
            for (int t = 0; t < 3; ++t)
                bfr[t] = *(const bf16x8*)&lb[(wc * 48 + t * 16 + col) * 64 + ca];
#pragma unroll
            for (int mr = 0; mr < 4; ++mr)
#pragma unroll
                for (int nc = 0; nc < 3; ++nc)
                    acc[mr][nc] = __builtin_amdgcn_mfma_f32_16x16x32_bf16(
                        af[mr], bfr[nc], acc[mr][nc], 0, 0, 0);
        }
        __builtin_amdgcn_sched_barrier(0);
        __builtin_amdgcn_s_barrier();
        cur = nxt;
    }

#pragma unroll
    for (int nc = 0; nc < 3; ++nc) {
        int n = n0 + wc * 48 + nc * 16 + col;
        float bv = bias[n];
#pragma unroll
        for (int mr = 0; mr < 4; ++mr) {
#pragma unroll
            for (int r = 0; r < 4; ++r) {
                int row = m0 + wr * 64 + mr * 16 + quad * 4 + r;
                Cmat[(size_t)row * N + n] = acc[mr][nc][r] + bv;
            }
        }
    }
}

// ---------------------------------------------------------------------------
// Fused causal flash attention — r10-exact (57.0-58.3us measured):
// 1024 blocks / 256 thr / 4 waves, T14 prefetch, P-in-register permuted-k
// PV, k-permuted V store, f32x4 lsum chains, heavy-first, T5 setprio.
// ---------------------------------------------------------------------------
__global__ __launch_bounds__(256) void attn_kernel(const bf16* __restrict__ qkv,
                                                   const bf16* __restrict__ Vt,
                                                   bf16* __restrict__ y,
                                                   int nGroups) {
    __shared__ bf16 ldsK[64 * KSTR];
    __shared__ bf16 ldsV[96 * VSTR];
    const int bid  = blockIdx.x;
    const int qt   = 31 - bid / nGroups;      // heavy blocks first
    const int g    = bid % nGroups;
    const int h    = g & 7, b = g >> 3;
    const int tid  = threadIdx.x;
    const int w    = tid >> 6, lane = tid & 63;
    const int col  = lane & 15, quad = lane >> 4;
    const float SCALE2 = 0.10206207261596577f * 1.4426950408889634f; // scale*log2e
    const float M0 = 24.0f;                    // static exponent shift (exact)
    const f32x4 zero = {0.f, 0.f, 0.f, 0.f};

    const bf16* qkvb = qkv + (size_t)b * T_ * QKN_;
    const bf16* Vtbh = Vt + (size_t)(b * H_ + h) * HS_ * T_;
    bf16* yb  = y + (size_t)b * T_ * C_;

    const int rbase = qt * 64 + w * 16;

    bf16x8 qf[3];
#pragma unroll
    for (int c = 0; c < 3; ++c)
        qf[c] = *(const bf16x8*)&qkvb[(size_t)(rbase + col) * QKN_ + h * HS_ + c * 32 + quad * 8];

    const bf16* pK[3]; const bf16* pV[3];
    bf16 *dK[3], *dV[3];
#pragma unroll
    for (int i = 0; i < 3; ++i) {
        int chunk = i * 256 + tid;
        int rK = chunk / 12, cK = chunk - rK * 12;
        pK[i] = qkvb + (size_t)rK * QKN_ + C_ + h * HS_ + cK * 8;
        dK[i] = &ldsK[rK * KSTR + cK * 8];
        int rV = chunk >> 3, cV = chunk & 7;
        pV[i] = Vtbh + (size_t)rV * T_ + cV * 8;
        dV[i] = &ldsV[rV * VSTR + cV * 8];
    }

    f32x4 o[6];
#pragma unroll
    for (int n2 = 0; n2 < 6; ++n2) o[n2] = zero;
    f32x4 lsum4 = zero;

    // prologue: prefetch jt=0 K/V into registers
    bf16x8 kreg[3], vreg[3];
#pragma unroll
    for (int i = 0; i < 3; ++i) {
        kreg[i] = *(const bf16x8*)pK[i];
        vreg[i] = *(const bf16x8*)pV[i];
        pK[i] += (size_t)64 * QKN_;
        pV[i] += 64;
    }

    const int njt = qt + 1;
    for (int jt = 0; jt < njt; ++jt) {
        int jb = jt * 64;
        __syncthreads();
        // write-late: regs -> LDS
#pragma unroll
        for (int i = 0; i < 3; ++i) {
            *(bf16x8*)dK[i] = kreg[i];
            *(bf16x8*)dV[i] = vreg[i];
        }
        __syncthreads();
        // issue-early: next tile's global loads fly under compute below
        if (jt + 1 < njt) {
#pragma unroll
            for (int i = 0; i < 3; ++i) {
                kreg[i] = *(const bf16x8*)pK[i];
                vreg[i] = *(const bf16x8*)pV[i];
                pK[i] += (size_t)64 * QKN_;
                pV[i] += 64;
            }
        }

        // QK^T: kf loaded per-nb (short live-range); T5 boost for MFMA cluster
        f32x4 st[4];
        __builtin_amdgcn_s_setprio(1);
#pragma unroll
        for (int nb = 0; nb < 4; ++nb) {
            st[nb] = zero;
#pragma unroll
            for (int c = 0; c < 3; ++c) {
                bf16x8 kf = *(const bf16x8*)&ldsK[(nb * 16 + col) * KSTR + c * 32 + quad * 8];
                st[nb] = __builtin_amdgcn_mfma_f32_16x16x32_bf16(
                    kf, qf[c], st[nb], 0, 0, 0);
            }
        }
        __builtin_amdgcn_s_setprio(0);

        if (jt == njt - 1) {
#pragma unroll
            for (int nb = 0; nb < 4; ++nb)
#pragma unroll
                for (int r = 0; r < 4; ++r) {
                    int jg = jb + nb * 16 + quad * 4 + r;
                    st[nb][r] = (jg <= rbase + col) ? fmaf(st[nb][r], SCALE2, -M0)
                                                    : NEG_BIG;
                }
        } else {
#pragma unroll
            for (int nb = 0; nb < 4; ++nb)
#pragma unroll
                for (int r = 0; r < 4; ++r)
                    st[nb][r] = fmaf(st[nb][r], SCALE2, -M0);
        }

#pragma unroll
        for (int nb = 0; nb < 4; ++nb) {
#pragma unroll
            for (int r = 0; r < 4; ++r)
                st[nb][r] = exp2f(st[nb][r]);
            lsum4 += st[nb];              // 4 independent FP chains
        }

        // Pack P as permuted-k B-operands (st stays in registers):
        // palo slot quad*8+j <-> k = (j<4?0:2)*16 + quad*4 + (j&3)
        // pahi slot quad*8+j <-> k = (j<4?1:3)*16 + quad*4 + (j&3)
        bf16x8 palo, pahi;
#pragma unroll
        for (int r = 0; r < 4; ++r) {
            palo[r]     = (bf16)st[0][r];
            palo[4 + r] = (bf16)st[2][r];
            pahi[r]     = (bf16)st[1][r];
            pahi[4 + r] = (bf16)st[3][r];
        }

        // V is k-permuted in storage: matching operand = contiguous b128
        __builtin_amdgcn_s_setprio(1);
#pragma unroll
        for (int n2 = 0; n2 < 6; ++n2) {
            const bf16* vrow = &ldsV[(n2 * 16 + col) * VSTR];
            bf16x8 vlo = *(const bf16x8*)&vrow[quad * 8];
            bf16x8 vhi = *(const bf16x8*)&vrow[32 + quad * 8];
            o[n2] = __builtin_amdgcn_mfma_f32_16x16x32_bf16(vlo, palo, o[n2], 0, 0, 0);
            o[n2] = __builtin_amdgcn_mfma_f32_16x16x32_bf16(vhi, pahi, o[n2], 0, 0, 0);
        }
        __builtin_amdgcn_s_setprio(0);
    }

    float lsum = (lsum4[0] + lsum4[1]) + (lsum4[2] + lsum4[3]);
    lsum += __shfl_xor(lsum, 16, 64);
    lsum += __shfl_xor(lsum, 32, 64);
    float linv = 1.0f / lsum;
#pragma unroll
    for (int n2 = 0; n2 < 6; ++n2) {
        bf16x4 pk = {(bf16)(o[n2][0] * linv), (bf16)(o[n2][1] * linv),
                     (bf16)(o[n2][2] * linv), (bf16)(o[n2][3] * linv)};
        *(bf16x4*)&yb[(size_t)(rbase + col) * C_ + h * HS_ + n2 * 16 + quad * 4] = pk;
    }
}

// ---------------------------------------------------------------------------
extern "C" void kernel_launch(void* const* d_in, const int* in_sizes, int n_in,
                              void* d_out, int out_size, void* d_ws, size_t ws_size,
                              hipStream_t stream) {
    (void)in_sizes; (void)n_in;
    const float* x      = (const float*)d_in[0];
    const float* W_attn = (const float*)d_in[1];
    const float* b_attn = (const float*)d_in[2];
    const float* W_proj = (const float*)d_in[3];
    const float* b_proj = (const float*)d_in[4];
    float* out = (float*)d_out;

    size_t e_wta = (size_t)QKN_ * C_;
    size_t e_wtp = (size_t)C_ * C_;
    size_t a_qkv = e_wta + e_wtp;
    size_t a_vt  = a_qkv + (size_t)M_ * QKN_;
    size_t a_yb  = a_vt + (size_t)M_ * C_;
    size_t needA = (a_yb + (size_t)M_ * C_) * sizeof(bf16);   // 67.6 MB
    size_t b_qkv = e_wta + e_wtp;
    size_t b_vt  = b_qkv + (size_t)T_ * QKN_;
    size_t b_yb  = b_vt + (size_t)T_ * C_;
    size_t needB = (b_yb + (size_t)T_ * C_) * sizeof(bf16);   // 20.4 MB

    if (ws_size >= needA) {
        bf16* Wt_attn = (bf16*)d_ws;
        bf16* Wt_proj = (bf16*)d_ws + e_wta;
        bf16* qkv     = (bf16*)d_ws + a_qkv;
        bf16* Vt      = (bf16*)d_ws + a_vt;
        bf16* yb      = (bf16*)d_ws + a_yb;
        bf16* xb      = yb;  // alias (xb dead before attn writes yb)
        prep_kernel<<<dim3(CONV_BLKS + TA_BLKS + TP_BLKS), 256, 0, stream>>>(
            x, xb, W_attn, Wt_attn, W_proj, Wt_proj);
        gemm_qkv<<<dim3(QKN_ / 128, M_ / 128), 256, 0, stream>>>(
            xb, Wt_attn, b_attn, qkv, Vt, M_, QKN_, C_);
        attn_kernel<<<dim3(32 * H_ * B_), 256, 0, stream>>>(qkv, Vt, yb, H_ * B_);
        gemm_proj<<<dim3(C_ / 96, M_ / 128), 256, 0, stream>>>(
            yb, Wt_proj, b_proj, out, M_, C_, C_);
    } else if (ws_size >= needB) {
        bf16* Wt_attn = (bf16*)d_ws;
        bf16* Wt_proj = (bf16*)d_ws + e_wta;
        bf16* qkv     = (bf16*)d_ws + b_qkv;
        bf16* Vt      = (bf16*)d_ws + b_vt;
        bf16* yb      = (bf16*)d_ws + b_yb;
        bf16* xb      = yb;  // alias per-batch
        transpose_kernel<<<dim3(QKN_ / 32, C_ / 32), dim3(32, 8), 0, stream>>>(W_attn, Wt_attn, C_, QKN_);
        transpose_kernel<<<dim3(C_ / 32, C_ / 32), dim3(32, 8), 0, stream>>>(W_proj, Wt_proj, C_, C_);
        for (int b = 0; b < B_; ++b) {
            const float* xf = x + (size_t)b * T_ * C_;
            float* outb     = out + (size_t)b * T_ * C_;
            convert_bf16_kernel<<<dim3(T_ * C_ / 8 / 256), 256, 0, stream>>>(xf, xb, T_ * C_ / 8);
            gemm_qkv<<<dim3(QKN_ / 128, T_ / 128), 256, 0, stream>>>(
                xb, Wt_attn, b_attn, qkv, Vt, T_, QKN_, C_);
            attn_kernel<<<dim3(32 * H_), 256, 0, stream>>>(qkv, Vt, yb, H_);
            gemm_proj<<<dim3(C_ / 96, T_ / 128), 256, 0, stream>>>(
                yb, Wt_proj, b_proj, outb, T_, C_, C_);
        }
    } else {
        sentinel_kernel<<<(out_size + 255) / 256, 256, 0, stream>>>(out, out_size);
    }
}